// Round 8
// baseline (726.842 us; speedup 1.0000x reference)
//
#include <hip/hip_runtime.h>
#include <hip/hip_fp16.h>
#include <math.h>

#define DD 128
#define CAP 64   // max facts per tail bucket; Poisson(10) => P(overflow) ~ 1e-30

typedef _Float16 half_t;
typedef __attribute__((ext_vector_type(8))) _Float16 half8;
typedef __attribute__((ext_vector_type(4))) float floatx4;

#define LDW 136  // for the legacy QB gemm only

// packed relu: x * (x > 0)  — ROCm 7.2 has no __hmax2
__device__ __forceinline__ __half2 relu2(__half2 x) {
    return __hmul2(x, __hgt2(x, __float2half2_rn(0.f)));
}

// DPP-fused add: t += dpp(t, CTRL); pure VALU, no LDS pipe.
template <int CTRL>
__device__ __forceinline__ float dpp_add(float x) {
    int y = __builtin_amdgcn_update_dpp(0, __float_as_int(x), CTRL, 0xf, 0xf, true);
    return x + __int_as_float(y);
}

// ---------------- one-time weight prep ---------------------------------------
// blocks 0-2: fragment-major f16 tables for Wh, Ws, Wr:
//   F[((t*4+kkI)*64+lane)*8 + j] = W[k][n],  n = t*16+(lane&15),
//   k = kkI*32+(lane>>4)*8+j   (exact mfma_16x16x32 B-fragment order)
// block 3: [n][k] transpose for Wqr (legacy QB gemm layout).
__global__ void wprep(const float* __restrict__ Wh, const float* __restrict__ Ws,
                      const float* __restrict__ Wr, const float* __restrict__ Wqr,
                      half_t* __restrict__ WhF, half_t* __restrict__ WsF,
                      half_t* __restrict__ WrF, half_t* __restrict__ WqrT) {
    int m = blockIdx.x;
    if (m < 3) {
        const float* W = m == 0 ? Wh : m == 1 ? Ws : Wr;
        half_t* F      = m == 0 ? WhF : m == 1 ? WsF : WrF;
        for (int idx = threadIdx.x; idx < 2048; idx += blockDim.x) {
            int lane = idx & 63, kkI = (idx >> 6) & 3, t = idx >> 8;
            int n = t * 16 + (lane & 15);
            int k0 = kkI * 32 + (lane >> 4) * 8;
            half_t tmp[8];
#pragma unroll
            for (int j = 0; j < 8; j++) tmp[j] = (half_t)W[(size_t)(k0 + j) * DD + n];
            *(half8*)(F + (size_t)idx * 8) = *(half8*)tmp;
        }
    } else {
        for (int i = threadIdx.x; i < DD * DD; i += blockDim.x) {
            int n = i >> 7, k = i & 127;
            WqrT[i] = (half_t)Wqr[(size_t)k * DD + n];
        }
    }
}

// ---------------- streaming dual-GEMM pack -----------------------------------
// Packed[row] = { f16(A@W1)[0..127] , f16(A@W2)[0..127] }  (512 B/row)
// 1024 thr = 16 waves; both W frag tables staged once into 64 KB LDS (one
// barrier per block); each wave owns an independent 16-row tile: A-fragments
// loaded straight from global (2 x float4 per kk), 64 MFMA, direct store.
__global__ __launch_bounds__(1024) void gemm_pack2v(
    const float* __restrict__ table, int M,
    const half_t* __restrict__ W1F, const half_t* __restrict__ W2F,
    __half* __restrict__ Packed) {
    __shared__ half_t WF[2 * 2048 * 8];   // exactly 64 KB
    int tid = threadIdx.x;
    for (int i = tid; i < 4096; i += 1024) {
        const half_t* src = (i < 2048) ? (W1F + (size_t)i * 8)
                                       : (W2F + (size_t)(i - 2048) * 8);
        *(half8*)(WF + (size_t)i * 8) = *(const half8*)src;
    }
    __syncthreads();

    int w = tid >> 6, lane = tid & 63;
    int nt = (M + 15) >> 4;
    for (int tile = blockIdx.x * 16 + w; tile < nt; tile += gridDim.x * 16) {
        int row = tile * 16 + (lane & 15);
        int rs = row < M ? row : M - 1;
        int k0 = (lane >> 4) * 8;
        half8 afr[4];
#pragma unroll
        for (int kkI = 0; kkI < 4; kkI++) {
            const float* p = table + (size_t)rs * DD + kkI * 32 + k0;
            float4 va = *(const float4*)p;
            float4 vb = *(const float4*)(p + 4);
            half8 a;
            a[0] = (half_t)va.x; a[1] = (half_t)va.y;
            a[2] = (half_t)va.z; a[3] = (half_t)va.w;
            a[4] = (half_t)vb.x; a[5] = (half_t)vb.y;
            a[6] = (half_t)vb.z; a[7] = (half_t)vb.w;
            afr[kkI] = a;
        }
#pragma unroll
        for (int m = 0; m < 2; m++) {
            floatx4 acc[8];
#pragma unroll
            for (int t = 0; t < 8; t++) acc[t] = (floatx4){0.f, 0.f, 0.f, 0.f};
#pragma unroll
            for (int t = 0; t < 8; t++)
#pragma unroll
                for (int kkI = 0; kkI < 4; kkI++) {
                    half8 b = *(const half8*)(WF +
                        (((size_t)(m * 8 + t) * 4 + kkI) * 64 + lane) * 8);
                    acc[t] = __builtin_amdgcn_mfma_f32_16x16x32_f16(afr[kkI], b, acc[t], 0, 0, 0);
                }
            int rbase = tile * 16 + (lane >> 4) * 4;
#pragma unroll
            for (int t = 0; t < 8; t++) {
                int col = t * 16 + (lane & 15);
#pragma unroll
                for (int i2 = 0; i2 < 4; i2++) {
                    int gr = rbase + i2;
                    if (gr < M)
                        Packed[(size_t)gr * 256 + m * 128 + col] = __float2half(acc[t][i2]);
                }
            }
        }
    }
}

// ---------------- MFMA GEMM (legacy layout; QB pass only, B=512) -------------
__global__ __launch_bounds__(256) void gemm_mfma(
    const float* __restrict__ table, const int* __restrict__ idx, int idxAdd, int M,
    const half_t* __restrict__ WT_g, const float* __restrict__ bias,
    float* __restrict__ OutF, __half* __restrict__ OutH) {
    __shared__ half_t WT[DD * LDW];
    __shared__ half_t As[64 * LDW];
    int tid = threadIdx.x;
    int lane = tid & 63;
    int w = tid >> 6;
    int rowf = lane & 15;
    int kgrp = (lane >> 4) * 8;

    for (int i = tid; i < 2048; i += 256) {
        int n = i >> 4, ch = i & 15;
        *(half8*)(WT + n * LDW + ch * 8) = *(const half8*)(WT_g + n * DD + ch * 8);
    }
    int tileM = blockIdx.x * 64;
    for (int i = tid; i < 2048; i += 256) {
        int row = i >> 5, c4 = i & 31;
        int gr = tileM + row;
        float4 v = make_float4(0.f, 0.f, 0.f, 0.f);
        if (gr < M) {
            int src = idx ? (idx[gr] + idxAdd) : gr;
            v = *(const float4*)(table + (size_t)src * DD + c4 * 4);
        }
        __half2 h01 = __floats2half2_rn(v.x, v.y);
        __half2 h23 = __floats2half2_rn(v.z, v.w);
        *(uint2*)(As + row * LDW + c4 * 4) = make_uint2(*(unsigned*)&h01, *(unsigned*)&h23);
    }
    __syncthreads();

    floatx4 acc[8];
#pragma unroll
    for (int t = 0; t < 8; t++) acc[t] = (floatx4){0.f, 0.f, 0.f, 0.f};
    const half_t* ap = As + (w * 16 + rowf) * LDW + kgrp;
    const half_t* bp0 = WT + rowf * LDW + kgrp;
#pragma unroll
    for (int kk = 0; kk < DD; kk += 32) {
        half8 a = *(const half8*)(ap + kk);
#pragma unroll
        for (int t = 0; t < 8; t++) {
            half8 b = *(const half8*)(bp0 + t * 16 * LDW + kk);
            acc[t] = __builtin_amdgcn_mfma_f32_16x16x32_f16(a, b, acc[t], 0, 0, 0);
        }
    }
    int orow = tileM + w * 16 + (lane >> 4) * 4;
#pragma unroll
    for (int t = 0; t < 8; t++) {
        int col = t * 16 + rowf;
        float bv = bias ? bias[col] : 0.f;
#pragma unroll
        for (int i = 0; i < 4; i++) {
            int gr = orow + i;
            if (gr < M) {
                float o = acc[t][i] + bv;
                if (OutF) OutF[(size_t)gr * DD + col] = o;
                if (OutH) OutH[(size_t)gr * DD + col] = __float2half(o);
            }
        }
    }
}

// ---------------- fused alpha + scatter over E facts (round-6 best) ----------
// 16 facts per wave: quarter-wave group g (16 lanes) handles facts e0+g+4j,
// j=0..3; each lane owns 8 cols. 12 gather-loads in flight per wave.
__global__ __launch_bounds__(256) void alpha_scatter(
    const __half* __restrict__ HB, const __half* __restrict__ RB,
    const __half* __restrict__ QB, const int* __restrict__ facts,
    const int* __restrict__ tail, const float* __restrict__ wa,
    const float* __restrict__ wa_b,
    int* __restrict__ cursor, int2* __restrict__ meta, int E) {
    int tid = threadIdx.x;
    int lane = tid & 63;
    int g = lane >> 4;       // quarter-wave group 0..3
    int cl = lane & 15;
    int c = cl * 8;          // 8 cols per lane
    int wv = (blockIdx.x * 256 + tid) >> 6;
    int e0 = wv * 16 + g;

    float4 wva = *(const float4*)(wa + c);
    float4 wvb = *(const float4*)(wa + c + 4);
    __half2 w0 = __halves2half2(__float2half(wva.x), __float2half(wva.y));
    __half2 w1 = __halves2half2(__float2half(wva.z), __float2half(wva.w));
    __half2 w2 = __halves2half2(__float2half(wvb.x), __float2half(wvb.y));
    __half2 w3 = __halves2half2(__float2half(wvb.z), __float2half(wvb.w));
    float wb = wa_b[0];

    bool v[4]; int2 bn[4]; int r[4]; int tl[4];
#pragma unroll
    for (int j = 0; j < 4; j++) {
        int f = e0 + j * 4;
        v[j] = f < E;
        int fc = v[j] ? f : 0;
        bn[j] = *(const int2*)(facts + (size_t)fc * 6);   // {b, n}
        r[j] = facts[(size_t)fc * 6 + 3];
        tl[j] = tail[fc];
    }

    // 12 independent 16B gathers in flight
    uint4 h[4], rr[4], q[4];
#pragma unroll
    for (int j = 0; j < 4; j++) {
        h[j]  = *(const uint4*)(HB + (size_t)bn[j].y * 256 + 128 + c);
        rr[j] = *(const uint4*)(RB + (size_t)(r[j] + 1) * 256 + 128 + c);
        q[j]  = *(const uint4*)(QB + (size_t)bn[j].x * DD + c);
    }

    float t[4];
#pragma unroll
    for (int j = 0; j < 4; j++) {
        __half2 p0 = relu2(__hadd2(__hadd2(*(__half2*)&h[j].x, *(__half2*)&rr[j].x),
                                   *(__half2*)&q[j].x));
        __half2 p1 = relu2(__hadd2(__hadd2(*(__half2*)&h[j].y, *(__half2*)&rr[j].y),
                                   *(__half2*)&q[j].y));
        __half2 p2 = relu2(__hadd2(__hadd2(*(__half2*)&h[j].z, *(__half2*)&rr[j].z),
                                   *(__half2*)&q[j].z));
        __half2 p3 = relu2(__hadd2(__hadd2(*(__half2*)&h[j].w, *(__half2*)&rr[j].w),
                                   *(__half2*)&q[j].w));
        __half2 t2 = __hfma2(p1, w1, __hmul2(p0, w0));
        t2 = __hfma2(p2, w2, t2);
        t2 = __hfma2(p3, w3, t2);
        t[j] = __half2float(__low2half(t2)) + __half2float(__high2half(t2));
    }

    // 16-lane row reduce (f32): lane cl==15 of each row holds the sum
#pragma unroll
    for (int j = 0; j < 4; j++) {
        t[j] = dpp_add<0x111>(t[j]);
        t[j] = dpp_add<0x112>(t[j]);
        t[j] = dpp_add<0x114>(t[j]);
        t[j] = dpp_add<0x118>(t[j]);
    }

    if (cl == 15) {
#pragma unroll
        for (int j = 0; j < 4; j++) {
            if (v[j]) {
                float a = 1.f / (1.f + __expf(-(t[j] + wb)));
                unsigned ab = (unsigned)__half_as_ushort(__float2half(a));
                int slot = atomicAdd(&cursor[tl[j]], 1);
                if (slot < CAP)
                    meta[(size_t)tl[j] * CAP + slot] =
                        make_int2(bn[j].y, (r[j] + 1) | (int)(ab << 16));
            }
        }
    }
}

// ---------------- segment aggregation direct to output (round-6 best) --------
__global__ __launch_bounds__(256) void agg_out(
    const __half* __restrict__ HB, const __half* __restrict__ RB,
    const int2* __restrict__ meta, const int* __restrict__ cursor,
    float* __restrict__ out, int T) {
    int w = threadIdx.x >> 6;
    int lane = threadIdx.x & 63;
    int seg = blockIdx.x * 4 + w;
    if (seg >= T) return;
    int cnt = cursor[seg];
    if (cnt > CAP) cnt = CAP;
    const int2* mp = meta + (size_t)seg * CAP;
    int co = lane * 2;
    float ax = 0.f, ay = 0.f;

#define ACC(hu, ru, y_)                                                        \
    {                                                                          \
        __half2 s = __hadd2(*(__half2*)&(hu), *(__half2*)&(ru));               \
        float al =                                                             \
            __half2float(__ushort_as_half((unsigned short)((unsigned)(y_) >> 16))); \
        float2 sf = __half22float2(s);                                         \
        ax = fmaf(al, sf.x, ax);                                               \
        ay = fmaf(al, sf.y, ay);                                               \
    }

    int i = 0;
    for (; i + 7 < cnt; i += 8) {
        int4 ma = *(const int4*)(mp + i);
        int4 mb = *(const int4*)(mp + i + 2);
        int4 mc = *(const int4*)(mp + i + 4);
        int4 md = *(const int4*)(mp + i + 6);
        unsigned h0 = *(const unsigned*)(HB + (size_t)ma.x * 256 + co);
        unsigned r0 = *(const unsigned*)(RB + (size_t)(ma.y & 0xFFFF) * 256 + co);
        unsigned h1 = *(const unsigned*)(HB + (size_t)ma.z * 256 + co);
        unsigned r1 = *(const unsigned*)(RB + (size_t)(ma.w & 0xFFFF) * 256 + co);
        unsigned h2 = *(const unsigned*)(HB + (size_t)mb.x * 256 + co);
        unsigned r2 = *(const unsigned*)(RB + (size_t)(mb.y & 0xFFFF) * 256 + co);
        unsigned h3 = *(const unsigned*)(HB + (size_t)mb.z * 256 + co);
        unsigned r3 = *(const unsigned*)(RB + (size_t)(mb.w & 0xFFFF) * 256 + co);
        unsigned h4 = *(const unsigned*)(HB + (size_t)mc.x * 256 + co);
        unsigned r4 = *(const unsigned*)(RB + (size_t)(mc.y & 0xFFFF) * 256 + co);
        unsigned h5 = *(const unsigned*)(HB + (size_t)mc.z * 256 + co);
        unsigned r5 = *(const unsigned*)(RB + (size_t)(mc.w & 0xFFFF) * 256 + co);
        unsigned h6 = *(const unsigned*)(HB + (size_t)md.x * 256 + co);
        unsigned r6 = *(const unsigned*)(RB + (size_t)(md.y & 0xFFFF) * 256 + co);
        unsigned h7 = *(const unsigned*)(HB + (size_t)md.z * 256 + co);
        unsigned r7 = *(const unsigned*)(RB + (size_t)(md.w & 0xFFFF) * 256 + co);
        ACC(h0, r0, ma.y); ACC(h1, r1, ma.w);
        ACC(h2, r2, mb.y); ACC(h3, r3, mb.w);
        ACC(h4, r4, mc.y); ACC(h5, r5, mc.w);
        ACC(h6, r6, md.y); ACC(h7, r7, md.w);
    }
    for (; i + 3 < cnt; i += 4) {
        int4 ma = *(const int4*)(mp + i);
        int4 mb = *(const int4*)(mp + i + 2);
        unsigned h0 = *(const unsigned*)(HB + (size_t)ma.x * 256 + co);
        unsigned r0 = *(const unsigned*)(RB + (size_t)(ma.y & 0xFFFF) * 256 + co);
        unsigned h1 = *(const unsigned*)(HB + (size_t)ma.z * 256 + co);
        unsigned r1 = *(const unsigned*)(RB + (size_t)(ma.w & 0xFFFF) * 256 + co);
        unsigned h2 = *(const unsigned*)(HB + (size_t)mb.x * 256 + co);
        unsigned r2 = *(const unsigned*)(RB + (size_t)(mb.y & 0xFFFF) * 256 + co);
        unsigned h3 = *(const unsigned*)(HB + (size_t)mb.z * 256 + co);
        unsigned r3 = *(const unsigned*)(RB + (size_t)(mb.w & 0xFFFF) * 256 + co);
        ACC(h0, r0, ma.y); ACC(h1, r1, ma.w);
        ACC(h2, r2, mb.y); ACC(h3, r3, mb.w);
    }
    for (; i < cnt; i++) {
        int2 m = mp[i];
        unsigned hu = *(const unsigned*)(HB + (size_t)m.x * 256 + co);
        unsigned ru = *(const unsigned*)(RB + (size_t)(m.y & 0xFFFF) * 256 + co);
        ACC(hu, ru, m.y);
    }
#undef ACC

    *(float2*)(out + (size_t)seg * DD + co) = make_float2(ax, ay);
}

extern "C" void kernel_launch(void* const* d_in, const int* in_sizes, int n_in,
                              void* d_out, int out_size, void* d_ws, size_t ws_size,
                              hipStream_t stream) {
    const float* hidden    = (const float*)d_in[0];
    const float* rel_table = (const float*)d_in[1];
    const float* Ws        = (const float*)d_in[2];
    const float* Wr        = (const float*)d_in[3];
    const float* Wqr_w     = (const float*)d_in[4];
    const float* Wqr_b     = (const float*)d_in[5];
    const float* wa_w      = (const float*)d_in[6];
    const float* wa_b      = (const float*)d_in[7];
    const float* Wh        = (const float*)d_in[8];
    const int* query_rel   = (const int*)d_in[9];
    const int* facts       = (const int*)d_in[10];
    const int* tail_index  = (const int*)d_in[11];

    int N     = in_sizes[0] / DD;   // 200000
    int Rrows = in_sizes[1] / DD;   // 481
    int B     = in_sizes[9];        // 512
    int E     = in_sizes[11];       // 1000000
    int T     = in_sizes[12];       // 100000

    char* ws = (char*)d_ws;
    size_t off = 0;
    auto alloc = [&](size_t bytes) -> void* {
        void* p = ws + off;
        off += (bytes + 255) & ~(size_t)255;
        return p;
    };
    __half* HB  = (__half*)alloc((size_t)N * 256 * 2);      // 102.4 MB
    __half* RB  = (__half*)alloc((size_t)Rrows * 256 * 2);  // 246 KB
    __half* QB  = (__half*)alloc((size_t)B * DD * 2);       // 128 KB
    int* cursor = (int*)alloc((size_t)T * 4);               // 400 KB
    int2* meta  = (int2*)alloc((size_t)T * CAP * 8);        // 51.2 MB
    half_t* WhF  = (half_t*)alloc((size_t)DD * DD * 2);     // 32 KB frag-major
    half_t* WsF  = (half_t*)alloc((size_t)DD * DD * 2);
    half_t* WrF  = (half_t*)alloc((size_t)DD * DD * 2);
    half_t* WqrT = (half_t*)alloc((size_t)DD * DD * 2);     // [n][k]

    (void)hipMemsetAsync(cursor, 0, (size_t)T * 4, stream);

    // one-time weight prep
    wprep<<<4, 256, 0, stream>>>(Wh, Ws, Wr, Wqr_w, WhF, WsF, WrF, WqrT);

    // HB = {f16(hidden @ Wh) || f16(hidden @ Ws)}   (Wh folded via linearity)
    int ntN = (N + 15) >> 4;
    gemm_pack2v<<<(ntN + 15) / 16, 1024, 0, stream>>>(hidden, N, WhF, WsF, HB);
    // RB = {f16(rel_table @ Wh) || f16(rel_table @ Wr)}
    int ntR = (Rrows + 15) >> 4;
    gemm_pack2v<<<(ntR + 15) / 16, 1024, 0, stream>>>(rel_table, Rrows, WhF, WrF, RB);
    // QB = f16(rel_table[query_rel+1] @ Wqr_w + Wqr_b)
    gemm_mfma<<<(B + 63) / 64, 256, 0, stream>>>(rel_table, query_rel, 1, B,
                                                 WqrT, Wqr_b, nullptr, QB);

    // alpha + scatter fused: 16 facts/wave, 12 gathers in flight
    alpha_scatter<<<(E + 63) / 64, 256, 0, stream>>>(HB, RB, QB, facts, tail_index,
                                                     wa_w, wa_b, cursor, meta, E);

    // out[t] = sum alpha * (hWh + hrWh)  — final GEMM eliminated by linearity
    agg_out<<<(T + 3) / 4, 256, 0, stream>>>(HB, RB, meta, cursor,
                                             (float*)d_out, T);
}